// Round 3
// baseline (548.573 us; speedup 1.0000x reference)
//
#include <hip/hip_runtime.h>

#define B_   4
#define C_   64
#define H_   128
#define W_   128
#define KS   7
#define G_   4
#define GC_  16
#define KK   49
#define PAD  3
#define TH   16
#define TW   16
#define HW_  (H_ * W_)
#define HALO_H 22
#define HALO_W 22
#define CSTRIDE 485           // dwords per halo channel (22*22+1, odd -> 2-way banks)
#define ZROWB 528             // bytes per z k-row (256 px * 2B + 16B pad)

typedef float f32x4  __attribute__((ext_vector_type(4)));
typedef short bf16x8 __attribute__((ext_vector_type(8)));
typedef unsigned int u32x4 __attribute__((ext_vector_type(4)));
typedef unsigned int u32x2 __attribute__((ext_vector_type(2)));

__device__ __forceinline__ unsigned f2bf(float f) {   // RNE float->bf16 (low 16)
    unsigned u = __float_as_uint(f);
    unsigned r = u + 0x7FFFu + ((u >> 16) & 1u);
    return r >> 16;
}

__global__ __launch_bounds__(256, 2) void invol_mfma2(
    const float* __restrict__ x,
    const float* __restrict__ cw,
    const float* __restrict__ bng,
    const float* __restrict__ bnb,
    const float* __restrict__ bnm,
    const float* __restrict__ bnv,
    float* __restrict__ out)
{
    __shared__ float halo[GC_ * CSTRIDE];                      // 31040 B
    __shared__ __align__(16) unsigned short z_sh[KK * (ZROWB / 2)]; // 25872 B
    __shared__ float sscale[KK], sbias[KK];

    const int tid  = threadIdx.x;
    const int lane = tid & 63;
    const int wv   = tid >> 6;        // wave 0..3
    const int l15  = lane & 15;
    const int l4   = lane >> 4;

    const int w0 = blockIdx.x * TW;
    const int h0 = blockIdx.y * TH;
    const int bz = blockIdx.z;        // b*G + g
    const int b  = bz >> 2;
    const int g  = bz & 3;

    // ---- BN constants ----
    if (tid < KK) {
        const int o = g * KK + tid;
        const float s = bng[o] * rsqrtf(bnv[o] + 1e-5f);
        sscale[tid] = s;
        sbias[tid]  = bnb[o] - bnm[o] * s;
    }

    // ---- stage halo: [c][22 rows][22 cols], channel stride 485 dwords ----
    const float* xg = x + (size_t)(b * C_ + g * GC_) * HW_;
    for (int i = tid; i < GC_ * HALO_H * HALO_W; i += 256) {
        const int c  = i / (HALO_H * HALO_W);
        const int r  = i - c * (HALO_H * HALO_W);
        const int hh = r / HALO_W;
        const int ww = r - hh * HALO_W;
        const int gh = h0 + hh - PAD;
        const int gw = w0 + ww - PAD;
        float v = 0.0f;
        if (gh >= 0 && gh < H_ && gw >= 0 && gw < W_)
            v = xg[c * HW_ + gh * W_ + gw];
        halo[c * CSTRIDE + hh * HALO_W + ww] = v;
    }

    // ---- A fragments: A[px][c], px = (wv*4+mt)*16 + l15 ----
    bf16x8 afr[4][2];
    {
        const float* xb = x + (size_t)b * C_ * HW_;
#pragma unroll
        for (int mt = 0; mt < 4; ++mt) {
            const int hh = h0 + wv * 4 + mt;
            const float* xp = xb + hh * W_ + (w0 + l15);
#pragma unroll
            for (int ks = 0; ks < 2; ++ks) {
                const int c0 = ks * 32 + l4 * 8;
                bf16x8 a;
#pragma unroll
                for (int j = 0; j < 8; ++j)
                    a[j] = (short)f2bf(xp[(size_t)(c0 + j) * HW_]);
                afr[mt][ks] = a;
            }
        }
    }

    // ---- B fragments: B[c][k], k = nt*16 + l15 (zero-padded past 49) ----
    bf16x8 bfr[4][2];
    {
#pragma unroll
        for (int nt = 0; nt < 4; ++nt) {
            const int kout = nt * 16 + l15;
            const bool kv = (kout < KK);
            const float* wp = cw + (size_t)(g * KK + (kv ? kout : 0)) * C_;
#pragma unroll
            for (int ks = 0; ks < 2; ++ks) {
                const int c0 = ks * 32 + l4 * 8;
                bf16x8 bb;
#pragma unroll
                for (int j = 0; j < 8; ++j)
                    bb[j] = kv ? (short)f2bf(wp[c0 + j]) : (short)0;
                bfr[nt][ks] = bb;
            }
        }
    }

    __syncthreads();   // halo + BN consts staged

    // ---- MFMA: z[px][k] ----
    f32x4 acc1[4][4];
#pragma unroll
    for (int mt = 0; mt < 4; ++mt)
#pragma unroll
        for (int nt = 0; nt < 4; ++nt) {
            f32x4 a = {0.f, 0.f, 0.f, 0.f};
            a = __builtin_amdgcn_mfma_f32_16x16x32_bf16(afr[mt][0], bfr[nt][0], a, 0, 0, 0);
            a = __builtin_amdgcn_mfma_f32_16x16x32_bf16(afr[mt][1], bfr[nt][1], a, 0, 0, 0);
            acc1[mt][nt] = a;
        }

    // ---- epilogue: BN+SiLU, pack 4 px -> ds_write_b64 into swizzled [k][px] ----
    // D layout: k = nt*16+l15 (col), px = (wv*4+mt)*16 + l4*4 + r (row)
#pragma unroll
    for (int nt = 0; nt < 4; ++nt) {
        const int k = nt * 16 + l15;
        if (k < KK) {
            const float sc = sscale[k];
            const float bi = sbias[k];
#pragma unroll
            for (int mt = 0; mt < 4; ++mt) {
                const int Y   = wv * 4 + mt;
                const int px0 = Y * 16 + l4 * 4;
                float v[4];
#pragma unroll
                for (int r = 0; r < 4; ++r) {
                    const float t = acc1[mt][nt][r] * sc + bi;
                    v[r] = __fdividef(t, 1.0f + __expf(-t));
                }
                u32x2 wpk;
                wpk[0] = f2bf(v[0]) | (f2bf(v[1]) << 16);
                wpk[1] = f2bf(v[2]) | (f2bf(v[3]) << 16);
                const int half = (px0 >> 3) & 1;             // = l4>>1
                const int blk  = 2 * Y + (half ^ ((Y >> 2) & 1));
                char* zp = (char*)z_sh + k * ZROWB + blk * 16 + (px0 & 7) * 2;
                *(u32x2*)zp = wpk;
            }
        }
    }

    __syncthreads();   // z visible

    // ---- involution (dual structure): thread = (c2, y), owns 16 x ----
    const int c2 = tid >> 4;
    const int y  = tid & 15;
    const int ybit = (y >> 2) & 1;

    float acc[16];
#pragma unroll
    for (int i = 0; i < 16; ++i) acc[i] = 0.0f;

    const float* hc = &halo[c2 * CSTRIDE];

#pragma unroll
    for (int kh = 0; kh < KS; ++kh) {
        const float* hr = hc + (y + kh) * HALO_W;
        float row[22];
#pragma unroll
        for (int j = 0; j < 22; ++j) row[j] = hr[j];   // -> ds_read2_b32 pairs

#pragma unroll
        for (int kw = 0; kw < KS; ++kw) {
            const int k = kh * KS + kw;
            const char* zb = (const char*)z_sh + k * ZROWB;
            const u32x4 q0 = *(const u32x4*)(zb + ((2 * y + (0 ^ ybit)) << 4));
            const u32x4 q1 = *(const u32x4*)(zb + ((2 * y + (1 ^ ybit)) << 4));
#pragma unroll
            for (int i = 0; i < 4; ++i) {
                const float zl0 = __uint_as_float(q0[i] << 16);
                const float zh0 = __uint_as_float(q0[i] & 0xFFFF0000u);
                acc[2 * i]     = fmaf(zl0, row[2 * i + kw],     acc[2 * i]);
                acc[2 * i + 1] = fmaf(zh0, row[2 * i + 1 + kw], acc[2 * i + 1]);
                const float zl1 = __uint_as_float(q1[i] << 16);
                const float zh1 = __uint_as_float(q1[i] & 0xFFFF0000u);
                acc[8 + 2 * i]     = fmaf(zl1, row[8 + 2 * i + kw],     acc[8 + 2 * i]);
                acc[8 + 2 * i + 1] = fmaf(zh1, row[8 + 2 * i + 1 + kw], acc[8 + 2 * i + 1]);
            }
        }
    }

    // ---- coalesced 16B stores: 4x float4 per thread ----
    float* og = out + (size_t)(b * C_ + g * GC_ + c2) * HW_ + (h0 + y) * W_ + w0;
#pragma unroll
    for (int i = 0; i < 4; ++i) {
        f32x4 v4 = { acc[4 * i], acc[4 * i + 1], acc[4 * i + 2], acc[4 * i + 3] };
        *(f32x4*)(og + 4 * i) = v4;
    }
}

extern "C" void kernel_launch(void* const* d_in, const int* in_sizes, int n_in,
                              void* d_out, int out_size, void* d_ws, size_t ws_size,
                              hipStream_t stream) {
    const float* x   = (const float*)d_in[0];
    const float* cw  = (const float*)d_in[1];
    const float* bng = (const float*)d_in[2];
    const float* bnb = (const float*)d_in[3];
    const float* bnm = (const float*)d_in[4];
    const float* bnv = (const float*)d_in[5];
    float* out = (float*)d_out;

    dim3 grid(W_ / TW, H_ / TH, B_ * G_);   // 8 x 8 x 16
    dim3 block(256);
    invol_mfma2<<<grid, block, 0, stream>>>(x, cw, bng, bnb, bnm, bnv, out);
}